// Round 11
// baseline (15630.093 us; speedup 1.0000x reference)
//
#include <hip/hip_runtime.h>
#include <math.h>

// ---------------- problem dims ----------------
#define VV 32000
#define HH 512
#define G3 1536   // 3*HH
#define TI 128    // encoder length
#define TO 64     // max decode length
#define NB 5      // beam width
#define NEGF (-1000000000.0f)

// ---------------- grid config ----------------
#define NWG 256
#define NTHR 256
#define KGRU 64   // WGs running encoder recurrence + decoder GRU
#define KPA 40    // WGs running attention+Wc phase (8 per beam)
#define LSTR 32   // words per counter/flag line (128B)

struct Params {
  const int* seq;
  const int* sosp;
  const float *emb, *eWi, *eWh, *ebi, *ebh;
  const float *dWi, *dWh, *dbi, *dbh;
  const float *Wc, *bc, *Wout, *bout;
  unsigned* bar;
  int *cur_tok, *toks, *pars, *ptop_i;
  float *gi0, *eout, *h0b, *h1b, *dch, *cc, *ptop_v, *psum, *scores;
  float* out;
};

// Relaxed agent-scope (coherence-point) ops for MUTABLE cross-WG data.
__device__ __forceinline__ float cldf(const float* p) {
  return __hip_atomic_load(p, __ATOMIC_RELAXED, __HIP_MEMORY_SCOPE_AGENT);
}
__device__ __forceinline__ void cstf(float* p, float v) {
  __hip_atomic_store(p, v, __ATOMIC_RELAXED, __HIP_MEMORY_SCOPE_AGENT);
}
__device__ __forceinline__ int cldi(const int* p) {
  return __hip_atomic_load(p, __ATOMIC_RELAXED, __HIP_MEMORY_SCOPE_AGENT);
}
__device__ __forceinline__ void csti(int* p, int v) {
  __hip_atomic_store(p, v, __ATOMIC_RELAXED, __HIP_MEMORY_SCOPE_AGENT);
}
__device__ __forceinline__ unsigned rldu(const unsigned* p) {
  return __hip_atomic_load(p, __ATOMIC_RELAXED, __HIP_MEMORY_SCOPE_AGENT);
}
typedef unsigned long long u64t;
union F2U { u64t u; float f[2]; };
__device__ __forceinline__ void cld2(float* d, const float* p) {
  F2U x; x.u = __hip_atomic_load((const u64t*)p, __ATOMIC_RELAXED, __HIP_MEMORY_SCOPE_AGENT);
  d[0] = x.f[0]; d[1] = x.f[1];
}
__device__ __forceinline__ void cst2(float* p, float a, float b) {
  F2U x; x.f[0] = a; x.f[1] = b;
  __hip_atomic_store((u64t*)p, x.u, __ATOMIC_RELAXED, __HIP_MEMORY_SCOPE_AGENT);
}

// One-time acquire: invalidates stale L1/L2 so PLAIN cached loads may be used
// for data that is immutable from this point on (r6/r7-proven correct).
__device__ __forceinline__ void acq_fence(const unsigned* a) {
  if (threadIdx.x == 0)
    (void)__hip_atomic_load(a, __ATOMIC_ACQUIRE, __HIP_MEMORY_SCOPE_AGENT);
  __syncthreads();
}

__device__ __forceinline__ void bar_arrive(unsigned* lines, int myline) {
  __syncthreads();
  if (threadIdx.x == 0)
    __hip_atomic_fetch_add(lines + myline * LSTR, 1u,
                           __ATOMIC_RELAXED, __HIP_MEMORY_SCOPE_AGENT);
}
template <int SLP>
__device__ __forceinline__ void bar_wait8(const unsigned* lines, unsigned tgt) {
  if (threadIdx.x < 64) {
    for (;;) {
      unsigned v = tgt;
      if (threadIdx.x < 8) v = rldu(lines + threadIdx.x * LSTR);
      if (__all(v >= tgt)) break;
      __builtin_amdgcn_s_sleep(SLP);
    }
  }
  __syncthreads();
}
__device__ __forceinline__ void bcast_store(unsigned* L, int NL, unsigned tok) {
  asm volatile("s_waitcnt vmcnt(0)" ::: "memory");  // own data at CP
  for (int i = 0; i < NL; i++)
    __hip_atomic_store(L + i * LSTR, tok, __ATOMIC_RELAXED, __HIP_MEMORY_SCOPE_AGENT);
}
template <int SLP>
__device__ __forceinline__ void leaf_wait(const unsigned* L, int grp, unsigned tok) {
  if (threadIdx.x == 0) {
    while (rldu(L + grp * LSTR) < tok) __builtin_amdgcn_s_sleep(SLP);
  }
  __syncthreads();
}

__device__ __forceinline__ float wredf(float v) {
#pragma unroll
  for (int o = 32; o; o >>= 1) v += __shfl_xor(v, o, 64);
  return v;
}

// Decoder GRU layer over KGRU WGs, weights register-resident.
template <int LAYER>
__device__ void dec_gru_reg(const Params& p, float* sm, int t, int ib, int ob,
                            const float (&wd)[12][8]) {
  const int wg = blockIdx.x, tid = threadIdx.x;
  const int lane = tid & 63, wv = tid >> 6;
  float* sx = sm;                 // [NB][HH]
  float* sh = sm + NB * HH;       // [NB][HH]
  float* fres = sm + 2 * NB * HH; // [48][NB]

  int ct[NB], pr[NB];
#pragma unroll
  for (int b = 0; b < NB; b++) {
    ct[b] = (LAYER == 0) ? cldi(&p.cur_tok[b]) : 0;
    pr[b] = (t == 0) ? b : cldi(&p.pars[(t - 1) * NB + b]);
  }
  for (int i = tid; i < NB * (HH / 2); i += NTHR) {  // 1280 pairs
    int b = i >> 8, c = (i & 255) << 1;
    float x2[2], h2[2];
    if (LAYER == 0) {
      const float* e = p.emb + (size_t)ct[b] * HH + c;  // read-only, cached
      x2[0] = e[0]; x2[1] = e[1];
    } else {
      cld2(x2, &p.dch[((size_t)(ob * 2 + 0) * NB + b) * HH + c]);
    }
    cld2(h2, &p.dch[((size_t)(ib * 2 + LAYER) * NB + pr[b]) * HH + c]);
    sx[b * HH + c] = x2[0]; sx[b * HH + c + 1] = x2[1];
    sh[b * HH + c] = h2[0]; sh[b * HH + c + 1] = h2[1];
  }
  __syncthreads();
#pragma unroll
  for (int k = 0; k < 12; k++) {
    const int m_ = k % 6;                  // f%6 == k%6 since f = wv*12 + k
    const int f = wv * 12 + k;
    const float* vecb = (m_ >= 3) ? sh : sx;
    float a0 = 0.f, a1 = 0.f, a2 = 0.f, a3 = 0.f, a4 = 0.f;
#pragma unroll
    for (int j = 0; j < 8; j++) {
      float wj = wd[k][j];
      int o = j * 64 + lane;
      a0 += wj * vecb[0 * HH + o];
      a1 += wj * vecb[1 * HH + o];
      a2 += wj * vecb[2 * HH + o];
      a3 += wj * vecb[3 * HH + o];
      a4 += wj * vecb[4 * HH + o];
    }
    float r0 = wredf(a0), r1 = wredf(a1), r2 = wredf(a2), r3 = wredf(a3), r4 = wredf(a4);
    if (lane == 0) {
      fres[f * NB + 0] = r0; fres[f * NB + 1] = r1; fres[f * NB + 2] = r2;
      fres[f * NB + 3] = r3; fres[f * NB + 4] = r4;
    }
  }
  __syncthreads();
  if (tid < 8 * NB) {
    int ul = tid / NB, b = tid - ul * NB;
    int u = wg * 8 + ul;
    const float* bi = p.dbi + LAYER * G3;
    const float* bh = p.dbh + LAYER * G3;
    float ir = fres[(ul * 6 + 0) * NB + b] + bi[u];
    float iz = fres[(ul * 6 + 1) * NB + b] + bi[HH + u];
    float inn = fres[(ul * 6 + 2) * NB + b] + bi[2 * HH + u];
    float hr = fres[(ul * 6 + 3) * NB + b] + bh[u];
    float hz = fres[(ul * 6 + 4) * NB + b] + bh[HH + u];
    float hn = fres[(ul * 6 + 5) * NB + b] + bh[2 * HH + u];
    float hp = sh[b * HH + u];
    float r = 1.f / (1.f + expf(-(ir + hr)));
    float z = 1.f / (1.f + expf(-(iz + hz)));
    float n = tanhf(inn + r * hn);
    cstf(&p.dch[((size_t)(ob * 2 + LAYER) * NB + b) * HH + u], (1.f - z) * n + z * hp);
  }
}

__global__ void __launch_bounds__(NTHR, 1) bsd_kernel(Params p) {
  const int wg = blockIdx.x, tid = threadIdx.x;
  const int lane = tid & 63, wv = tid >> 6;
  __shared__ float sm[5504];
  __shared__ unsigned s_mrg;

  unsigned* c1A = p.bar + 0 * LSTR;    // 8 lines
  unsigned* c2A = p.bar + 8 * LSTR;    // 8
  unsigned* c3A = p.bar + 16 * LSTR;   // 8
  unsigned* c3F = p.bar + 24 * LSTR;   // 1
  unsigned* c5A = p.bar + 32 * LSTR;   // 8
  unsigned* c5F = p.bar + 40 * LSTR;   // 1
  unsigned* ceA = p.bar + 48 * LSTR;   // 8
  unsigned* cgA = p.bar + 56 * LSTR;   // 8
  unsigned* f6L = p.bar + 64 * LSTR;   // 16 flag6 leaves
  unsigned* f3L = p.bar + 80 * LSTR;   // 16
  unsigned* feL = p.bar + 96 * LSTR;   // 16 fenc leaves

  // ========== E0: gi0[t][row] = emb[seq[t]] . eWi0[row] + ebi0[row]; zero h ==========
  {
    if (wg == 0) {
      for (int i = tid; i < 2 * HH; i += NTHR) { cstf(&p.h0b[i], 0.f); cstf(&p.h1b[i], 0.f); }
    }
    for (int lr = wv; lr < 6; lr += 4) {
      int row = wg * 6 + lr;
      const float* W = p.eWi + (size_t)row * HH;
      float w0[8];
#pragma unroll
      for (int j = 0; j < 8; j++) w0[j] = W[j * 64 + lane];
      float bi = p.ebi[row];
      for (int t = 0; t < TI; t++) {
        const float* x = p.emb + (size_t)p.seq[t] * HH;
        float s = 0.f;
#pragma unroll
        for (int j = 0; j < 8; j++) s += w0[j] * x[j * 64 + lane];
        s = wredf(s);
        if (lane == 0) cstf(&p.gi0[(size_t)t * G3 + row], s + bi);
      }
    }
  }
  bar_arrive(cgA, wg & 7);
  bar_wait8<16>(cgA, 32u);
  acq_fence(cgA);   // gi0 is immutable from here: plain cached loads are safe

  // ========== E1: recurrence on KGRU WGs, register weights, 129 barriers ==========
  if (wg < KGRU) {
    float wreg[24][8];  // original j*64+lane mapping (bitwise-preserving)
    if (wv < 2) {
#pragma unroll
      for (int uu = 0; uu < 4; uu++) {
        int u = wg * 8 + wv * 4 + uu;
#pragma unroll
        for (int g = 0; g < 3; g++) {
          const float* W = p.eWh + (size_t)(g * HH + u) * HH;
#pragma unroll
          for (int j = 0; j < 8; j++) wreg[uu * 3 + g][j] = W[j * 64 + lane];
        }
      }
    } else {
#pragma unroll
      for (int uu = 0; uu < 4; uu++) {
        int u = wg * 8 + (wv - 2) * 4 + uu;
#pragma unroll
        for (int g = 0; g < 3; g++) {
          const float* Wi1 = p.eWi + (size_t)G3 * HH + (size_t)(g * HH + u) * HH;
          const float* Wh1 = p.eWh + (size_t)G3 * HH + (size_t)(g * HH + u) * HH;
#pragma unroll
          for (int j = 0; j < 8; j++) {
            wreg[uu * 6 + g][j] = Wi1[j * 64 + lane];
            wreg[uu * 6 + 3 + g][j] = Wh1[j * 64 + lane];
          }
        }
      }
    }
    float* smh0 = sm;        // staged h0b[sIn]  (512)
    float* smh1 = sm + 512;  // staged h1b[sOut] (512)
    for (int T = 0; T <= TI; T++) {
      const int sIn = T & 1, sOut = sIn ^ 1;
      {
        int c = tid << 1;  // pair base col
        float a2[2], b2[2];
        cld2(a2, &p.h0b[sIn * HH + c]);
        cld2(b2, &p.h1b[sOut * HH + c]);
        smh0[c] = a2[0]; smh0[c + 1] = a2[1];
        smh1[c] = b2[0]; smh1[c + 1] = b2[1];
      }
      __syncthreads();
      if (wv < 2) {
        if (T < TI) {
          float hv[8];
#pragma unroll
          for (int j = 0; j < 8; j++) hv[j] = smh0[j * 64 + lane];
          float garr[4][3];
#pragma unroll
          for (int uu = 0; uu < 4; uu++) {
#pragma unroll
            for (int gg = 0; gg < 3; gg++) {
              float s = 0.f;
#pragma unroll
              for (int j = 0; j < 8; j++) s += wreg[uu * 3 + gg][j] * hv[j];
              garr[uu][gg] = wredf(s);
            }
          }
          if (lane == 0) {
            const float* gr = p.gi0 + (size_t)T * G3;  // plain cached
#pragma unroll
            for (int up = 0; up < 2; up++) {
              int u0 = wg * 8 + wv * 4 + up * 2;
              float outv[2];
#pragma unroll
              for (int e = 0; e < 2; e++) {
                int uu = up * 2 + e;
                float ir = gr[u0 + e], iz = gr[HH + u0 + e], inn = gr[2 * HH + u0 + e];
                float hr = garr[uu][0] + p.ebh[u0 + e];
                float hz = garr[uu][1] + p.ebh[HH + u0 + e];
                float hn = garr[uu][2] + p.ebh[2 * HH + u0 + e];
                float r = 1.f / (1.f + expf(-(ir + hr)));
                float z = 1.f / (1.f + expf(-(iz + hz)));
                float n = tanhf(inn + r * hn);
                outv[e] = (1.f - z) * n + z * smh0[u0 + e];
              }
              cst2(&p.h0b[sOut * HH + u0], outv[0], outv[1]);
            }
          }
        }
      } else {
        if (T >= 1) {
          float xv[8], hv[8];
#pragma unroll
          for (int j = 0; j < 8; j++) { xv[j] = smh0[j * 64 + lane]; hv[j] = smh1[j * 64 + lane]; }
          float giarr[4][3], gharr[4][3];
#pragma unroll
          for (int uu = 0; uu < 4; uu++) {
#pragma unroll
            for (int gg = 0; gg < 3; gg++) {
              float si = 0.f, s2 = 0.f;
#pragma unroll
              for (int j = 0; j < 8; j++) {
                si += wreg[uu * 6 + gg][j] * xv[j];
                s2 += wreg[uu * 6 + 3 + gg][j] * hv[j];
              }
              giarr[uu][gg] = wredf(si);
              gharr[uu][gg] = wredf(s2);
            }
          }
          if (lane == 0) {
            const float* bi = p.ebi + G3;
            const float* bh = p.ebh + G3;
#pragma unroll
            for (int up = 0; up < 2; up++) {
              int u0 = wg * 8 + (wv - 2) * 4 + up * 2;
              float outv[2];
#pragma unroll
              for (int e = 0; e < 2; e++) {
                int uu = up * 2 + e;
                float ir = giarr[uu][0] + bi[u0 + e], iz = giarr[uu][1] + bi[HH + u0 + e],
                      inn = giarr[uu][2] + bi[2 * HH + u0 + e];
                float hr = gharr[uu][0] + bh[u0 + e], hz = gharr[uu][1] + bh[HH + u0 + e],
                      hn = gharr[uu][2] + bh[2 * HH + u0 + e];
                float r = 1.f / (1.f + expf(-(ir + hr)));
                float z = 1.f / (1.f + expf(-(iz + hz)));
                float n = tanhf(inn + r * hn);
                outv[e] = (1.f - z) * n + z * smh1[u0 + e];
              }
              cst2(&p.h1b[sIn * HH + u0], outv[0], outv[1]);
              cst2(&p.eout[(size_t)(T - 1) * HH + u0], outv[0], outv[1]);
            }
          }
        }
      }
      bar_arrive(ceA, wg & 7);
      bar_wait8<4>(ceA, (unsigned)(8 * (T + 1)));
    }
    if (wg == 0 && tid == 0) bcast_store(feL, 16, 1u);
  } else {
    leaf_wait<64>(feL, wg >> 4, 1u);  // slow poll: eventual wake, no storm
  }

  // ---- load decoder GRU weights into registers (KGRU WGs), both layers ----
  float wdec[2][12][8];
  if (wg < KGRU) {
#pragma unroll
    for (int k = 0; k < 12; k++) {
      const int f = wv * 12 + k;
      const int ul = f / 6, m_ = f % 6;
      const int u = wg * 8 + ul;
      const float* W0 = (m_ < 3 ? p.dWi : p.dWh) + (size_t)((m_ % 3) * HH + u) * HH;
      const float* W1 = (m_ < 3 ? p.dWi : p.dWh) + (size_t)G3 * HH + (size_t)((m_ % 3) * HH + u) * HH;
#pragma unroll
      for (int j = 0; j < 8; j++) { wdec[0][k][j] = W0[j * 64 + lane]; wdec[1][k][j] = W1[j * 64 + lane]; }
    }
  }

  // ========== D0: broadcast enc_hidden to beams, init tokens/scores ==========
  {
    for (int i = tid + wg * NTHR; i < 2 * NB * (HH / 2); i += NWG * NTHR) {  // 2560 pairs
      int l = i / (NB * (HH / 2));
      int rem = i - l * (NB * (HH / 2));
      int b = rem >> 8, c = (rem & 255) << 1;
      float h2[2];
      if (l == 0) cld2(h2, &p.h0b[c]); else cld2(h2, &p.h1b[c]);
      cst2(&p.dch[(size_t)l * NB * HH + b * HH + c], h2[0], h2[1]);
    }
    if (wg == 0 && tid < NB) {
      csti(&p.cur_tok[tid], p.sosp[0]);
      cstf(&p.scores[tid], (tid == 0) ? 0.f : NEGF);
    }
  }
  bar_arrive(cgA, wg & 7);
  bar_wait8<16>(cgA, 64u);
  acq_fence(cgA);   // eout is immutable from here: plain cached loads are safe

  // ========== decoder: 64 steps ==========
  for (int t = 0; t < TO; t++) {
    const int ib = t & 1, ob = ib ^ 1;

    if (wg < KGRU) {
      // step-t inputs (cur_tok/pars/scores) ready; only GRU WGs need them.
      leaf_wait<8>(f6L, wg >> 4, (unsigned)t);
      dec_gru_reg<0>(p, sm, t, ib, ob, wdec[0]);
      bar_arrive(c1A, wg & 7);
      bar_wait8<4>(c1A, (unsigned)(8 * (t + 1)));
      dec_gru_reg<1>(p, sm, t, ib, ob, wdec[1]);
      bar_arrive(c2A, wg & 7);
    }

    // ---- PA: attention + ctx + Wc + tanh (40 WGs, 8 per beam) ----
    if (wg < KPA) {
      bar_wait8<4>(c2A, (unsigned)(8 * (t + 1)));
      const int b = wg / 8, q = wg % 8;
      float* srnn = sm;                  // 512
      float* sp = sm + 512;              // 128
      float* cpart = sm + 640;           // [4][512]
      float* sctx = sm + 2688;           // 512
      for (int i = tid; i < HH / 2; i += NTHR) {
        float r2[2];
        cld2(r2, &p.dch[((size_t)(ob * 2 + 1) * NB + b) * HH + i * 2]);
        srnn[i * 2] = r2[0]; srnn[i * 2 + 1] = r2[1];
      }
      __syncthreads();
      for (int j = wv; j < TI; j += 4) {
        const float* E = p.eout + (size_t)j * HH;  // plain cached (immutable)
        float s = 0.f;
#pragma unroll
        for (int k2 = 0; k2 < 8; k2++) s += srnn[k2 * 64 + lane] * E[k2 * 64 + lane];
        s = wredf(s);
        if (lane == 0) sp[j] = s;
      }
      __syncthreads();
      if (wv == 0) {
        float v0 = sp[lane], v1 = sp[64 + lane];
        float mx = fmaxf(v0, v1);
#pragma unroll
        for (int o = 32; o; o >>= 1) mx = fmaxf(mx, __shfl_xor(mx, o, 64));
        float e0 = expf(v0 - mx), e1 = expf(v1 - mx);
        float ss = wredf(e0 + e1);
        sp[lane] = e0 / ss;
        sp[64 + lane] = e1 / ss;
      }
      __syncthreads();
      {  // ctx partials (plain cached eout, original col mapping)
        float cp[8];
#pragma unroll
        for (int k2 = 0; k2 < 8; k2++) cp[k2] = 0.f;
        for (int j = wv; j < TI; j += 4) {
          float spj = sp[j];
          const float* E = p.eout + (size_t)j * HH;
#pragma unroll
          for (int k2 = 0; k2 < 8; k2++) cp[k2] += spj * E[k2 * 64 + lane];
        }
#pragma unroll
        for (int k2 = 0; k2 < 8; k2++) cpart[wv * HH + k2 * 64 + lane] = cp[k2];
      }
      __syncthreads();
      for (int i = tid; i < HH; i += NTHR)
        sctx[i] = ((cpart[0 * HH + i] + cpart[1 * HH + i]) + cpart[2 * HH + i]) + cpart[3 * HH + i];
      __syncthreads();
      for (int k = wv; k < 64; k += 4) {
        int u = q * 64 + k;
        const float* W = p.Wc + (size_t)u * (2 * HH);
        float s0 = 0.f, s1 = 0.f;
#pragma unroll
        for (int j = 0; j < 8; j++) {
          int o = j * 64 + lane;
          s0 += W[o] * srnn[o];
          s1 += W[HH + o] * sctx[o];
        }
        float r0 = wredf(s0), r1 = wredf(s1);
        if (lane == 0) {
          float val = tanhf(r0 + r1 + p.bc[u]);
#pragma unroll
          for (int m = 0; m < 8; m++)   // 8 mirrors: cuts same-addr contention 8x
            cstf(&p.cc[(size_t)m * (NB * HH) + b * HH + u], val);
        }
      }
      // last-man over PA: line-last -> final line -> bcast f3L
      __syncthreads();
      if (tid == 0) {
        unsigned o1 = __hip_atomic_fetch_add(c3A + (wg & 7) * LSTR, 1u,
                                             __ATOMIC_RELAXED, __HIP_MEMORY_SCOPE_AGENT);
        if (o1 == (unsigned)(5 * (t + 1) - 1)) {
          unsigned o2 = __hip_atomic_fetch_add(c3F, 1u,
                                               __ATOMIC_RELAXED, __HIP_MEMORY_SCOPE_AGENT);
          if (o2 == (unsigned)(8 * (t + 1) - 1))
            bcast_store(f3L, 16, (unsigned)(t + 1));
        }
      }
    }
    // everyone waits for cc ready (ordered through PA chain)
    if (wg < KGRU) leaf_wait<8>(f3L, wg >> 4, (unsigned)(t + 1));
    else           leaf_wait<32>(f3L, wg >> 4, (unsigned)(t + 1));

    // ---- P5: logits chunk (125 rows/WG) + per-beam partial top5 + exp-sum ----
    {
      float* scc = sm;            // [NB][HH]
      float* slg = sm + NB * HH;  // [NB][125]
      const float* ccm = p.cc + (size_t)(wg & 7) * (NB * HH);  // mirror copy
      for (int i = tid; i < NB * (HH / 2); i += NTHR) {
        int b = i >> 8, c = (i & 255) << 1;
        float c2v[2];
        cld2(c2v, &ccm[b * HH + c]);
        scc[b * HH + c] = c2v[0]; scc[b * HH + c + 1] = c2v[1];
      }
      __syncthreads();
      const int vbase = wg * 125;
      float wnxt[8];
      {
        const float* W = p.Wout + (size_t)(vbase + wv) * HH;
#pragma unroll
        for (int j = 0; j < 8; j++) wnxt[j] = W[j * 64 + lane];
      }
      for (int r = wv; r < 125; r += 4) {
        float wcur[8];
#pragma unroll
        for (int j = 0; j < 8; j++) wcur[j] = wnxt[j];
        if (r + 4 < 125) {
          const float* W2 = p.Wout + (size_t)(vbase + r + 4) * HH;
#pragma unroll
          for (int j = 0; j < 8; j++) wnxt[j] = W2[j * 64 + lane];
        }
        float a0 = 0.f, a1 = 0.f, a2 = 0.f, a3 = 0.f, a4 = 0.f;
#pragma unroll
        for (int j = 0; j < 8; j++) {
          float wj = wcur[j];
          int o = j * 64 + lane;
          a0 += wj * scc[0 * HH + o];
          a1 += wj * scc[1 * HH + o];
          a2 += wj * scc[2 * HH + o];
          a3 += wj * scc[3 * HH + o];
          a4 += wj * scc[4 * HH + o];
        }
        float r0 = wredf(a0), r1 = wredf(a1), r2 = wredf(a2), r3 = wredf(a3), r4 = wredf(a4);
        if (lane == 0) {
          float bo = p.bout[vbase + r];
          slg[0 * 125 + r] = r0 + bo;
          slg[1 * 125 + r] = r1 + bo;
          slg[2 * 125 + r] = r2 + bo;
          slg[3 * 125 + r] = r3 + bo;
          slg[4 * 125 + r] = r4 + bo;
        }
      }
      __syncthreads();
      if (wv == 0) {
        for (int b = 0; b < NB; b++) {
          float s0 = (lane < 125) ? expf(slg[b * 125 + lane]) : 0.f;
          float s1 = (lane + 64 < 125) ? expf(slg[b * 125 + lane + 64]) : 0.f;
          float ss = wredf(s0 + s1);
          if (lane == 0) cstf(&p.psum[wg * NB + b], ss);
        }
      } else if (wv == 1 && lane < NB) {
        int b = lane;
        float bv[5]; int bidx[5];
#pragma unroll
        for (int k = 0; k < 5; k++) { bv[k] = -INFINITY; bidx[k] = 0x7fffffff; }
        for (int r = 0; r < 125; r++) {
          float v = slg[b * 125 + r];
          if (v > bv[4]) {  // strict >: equal values keep earlier (lower) index
            int k = 4;
            while (k > 0 && v > bv[k - 1]) { bv[k] = bv[k - 1]; bidx[k] = bidx[k - 1]; k--; }
            bv[k] = v; bidx[k] = vbase + r;
          }
        }
#pragma unroll
        for (int k = 0; k < 5; k++) {
          cstf(&p.ptop_v[(wg * NB + b) * 5 + k], bv[k]);
          csti(&p.ptop_i[(wg * NB + b) * 5 + k], bidx[k]);
        }
      }
    }

    // ---- last-man selection: final P5 arriver performs the merge ----
    __syncthreads();  // all waves' psum/ptop stores vm-drained (at CP)
    if (tid == 0) {
      unsigned m = 0;
      unsigned o1 = __hip_atomic_fetch_add(c5A + (wg & 7) * LSTR, 1u,
                                           __ATOMIC_RELAXED, __HIP_MEMORY_SCOPE_AGENT);
      if (o1 == (unsigned)(32 * (t + 1) - 1)) {
        unsigned o2 = __hip_atomic_fetch_add(c5F, 1u,
                                             __ATOMIC_RELAXED, __HIP_MEMORY_SCOPE_AGENT);
        if (o2 == (unsigned)(8 * (t + 1) - 1)) m = 1;
      }
      s_mrg = m;
    }
    __syncthreads();

    // ---- P6 merge (performed by the single last-arriving WG) ----
    if (s_mrg) {
      float* sls = sm;               // [5]
      float* smv = sm + 8;           // [5][5]
      int* smi = (int*)(sm + 40);    // [5][5]
      for (int b = wv; b < NB; b += 4) {
        float q0 = cldf(&p.psum[(lane + 0) * NB + b]);
        float q1 = cldf(&p.psum[(lane + 64) * NB + b]);
        float q2 = cldf(&p.psum[(lane + 128) * NB + b]);
        float q3 = cldf(&p.psum[(lane + 192) * NB + b]);
        float ssum = wredf((q0 + q1) + (q2 + q3));
        float bv[5]; int bix[5];
#pragma unroll
        for (int k = 0; k < 5; k++) { bv[k] = -INFINITY; bix[k] = 0x7fffffff; }
        for (int g = 0; g < 4; g++) {
          int w = lane + g * 64;
#pragma unroll
          for (int k = 0; k < 5; k++) {
            float v = cldf(&p.ptop_v[((size_t)w * NB + b) * 5 + k]);
            int id = cldi(&p.ptop_i[((size_t)w * NB + b) * 5 + k]);
            if (v > bv[4] || (v == bv[4] && id < bix[4])) {
              int kk = 4;
              while (kk > 0 && (v > bv[kk - 1] || (v == bv[kk - 1] && id < bix[kk - 1]))) {
                bv[kk] = bv[kk - 1]; bix[kk] = bix[kk - 1]; kk--;
              }
              bv[kk] = v; bix[kk] = id;
            }
          }
        }
#pragma unroll
        for (int off = 1; off < 64; off <<= 1) {
          float ov[5]; int oi[5];
#pragma unroll
          for (int k = 0; k < 5; k++) { ov[k] = __shfl_xor(bv[k], off, 64); oi[k] = __shfl_xor(bix[k], off, 64); }
          float nv[5]; int ni[5];
          int i2 = 0, j2 = 0;
#pragma unroll
          for (int k = 0; k < 5; k++) {
            bool ta = (bv[i2] > ov[j2]) || (bv[i2] == ov[j2] && bix[i2] < oi[j2]);
            if (ta) { nv[k] = bv[i2]; ni[k] = bix[i2]; i2++; }
            else { nv[k] = ov[j2]; ni[k] = oi[j2]; j2++; }
          }
#pragma unroll
          for (int k = 0; k < 5; k++) { bv[k] = nv[k]; bix[k] = ni[k]; }
        }
        if (lane == 0) {
          sls[b] = logf(ssum);
#pragma unroll
          for (int k = 0; k < 5; k++) { smv[b * 5 + k] = bv[k]; smi[b * 5 + k] = bix[k]; }
        }
      }
      __syncthreads();
      if (tid == 0) {
        float cand[25]; int ctok[25];
        for (int b = 0; b < NB; b++) {
          float sb = cldf(&p.scores[b]), lb = sls[b];
#pragma unroll
          for (int k = 0; k < 5; k++) {
            cand[b * 5 + k] = sb + (smv[b * 5 + k] - lb);
            ctok[b * 5 + k] = smi[b * 5 + k];
          }
        }
        float s5[5]; int f5[5];
#pragma unroll
        for (int k = 0; k < 5; k++) { s5[k] = -INFINITY; f5[k] = 0x7fffffff; }
        for (int f = 0; f < 25; f++) {
          float v = cand[f];
          if (v > s5[4]) {
            int k = 4;
            while (k > 0 && v > s5[k - 1]) { s5[k] = s5[k - 1]; f5[k] = f5[k - 1]; k--; }
            s5[k] = v; f5[k] = f;
          }
        }
        for (int j2 = 0; j2 < 5; j2++) {
          int fl = f5[j2];
          csti(&p.pars[t * NB + j2], fl / 5);
          csti(&p.toks[t * NB + j2], ctok[fl]);
          csti(&p.cur_tok[j2], ctok[fl]);
        }
        for (int j2 = 0; j2 < 5; j2++) cstf(&p.scores[j2], s5[j2]);
        bcast_store(f6L, 16, (unsigned)(t + 1));
      }
      __syncthreads();
    }
  }

  // ========== F: backtrack and write output (seq as float, then score) ==========
  if (wg == 0) {
    leaf_wait<16>(f6L, 0, (unsigned)TO);  // final merge (possibly other WG) done
    if (tid == 0) {
      int best = 0;
      float bvv = cldf(&p.scores[0]);
      for (int j = 1; j < NB; j++) {
        float sj = cldf(&p.scores[j]);
        if (sj > bvv) { bvv = sj; best = j; }
      }
      int beam = best;
      for (int tt = TO - 1; tt >= 0; tt--) {
        p.out[tt] = (float)cldi(&p.toks[tt * NB + beam]);
        beam = cldi(&p.pars[tt * NB + beam]);
      }
      p.out[TO] = bvv;
    }
  }
}

extern "C" void kernel_launch(void* const* d_in, const int* in_sizes, int n_in,
                              void* d_out, int out_size, void* d_ws, size_t ws_size,
                              hipStream_t stream) {
  (void)in_sizes; (void)n_in; (void)out_size; (void)ws_size;
  Params p;
  p.seq  = (const int*)d_in[0];
  p.sosp = (const int*)d_in[3];
  p.emb  = (const float*)d_in[4];
  p.eWi  = (const float*)d_in[5];
  p.eWh  = (const float*)d_in[6];
  p.ebi  = (const float*)d_in[7];
  p.ebh  = (const float*)d_in[8];
  p.dWi  = (const float*)d_in[9];
  p.dWh  = (const float*)d_in[10];
  p.dbi  = (const float*)d_in[11];
  p.dbh  = (const float*)d_in[12];
  p.Wc   = (const float*)d_in[13];
  p.bc   = (const float*)d_in[14];
  p.Wout = (const float*)d_in[15];
  p.bout = (const float*)d_in[16];

  char* w = (char*)d_ws;
  size_t off = 0;
  auto alloc = [&](size_t words) -> char* {
    char* r = w + off;
    off += words * 4;
    off = (off + 255) & ~(size_t)255;
    return r;
  };
  p.bar     = (unsigned*)alloc(120 * LSTR);   // 112 lines used (memset below)
  p.cur_tok = (int*)alloc(8);
  p.toks    = (int*)alloc(TO * NB);
  p.pars    = (int*)alloc(TO * NB);
  p.ptop_i  = (int*)alloc(NWG * NB * 5);
  p.gi0     = (float*)alloc((size_t)TI * G3);
  p.eout    = (float*)alloc((size_t)TI * HH);
  p.h0b     = (float*)alloc(2 * HH);
  p.h1b     = (float*)alloc(2 * HH);
  p.dch     = (float*)alloc(2 * 2 * NB * HH);
  p.cc      = (float*)alloc(8 * NB * HH);     // 8 mirror copies
  p.ptop_v  = (float*)alloc(NWG * NB * 5);
  p.psum    = (float*)alloc(NWG * NB);
  p.scores  = (float*)alloc(8);
  p.out     = (float*)d_out;

  (void)hipMemsetAsync(d_ws, 0, 120 * LSTR * 4, stream);  // zero all lines
  // Plain launch: 256 WGs x 256 thr at 1 WG/CU on 256 CUs -> co-resident.
  // hipLaunchCooperativeKernel silently rejects at VGPR=256 (r4/r5 failure).
  bsd_kernel<<<dim3(NWG), dim3(NTHR), 0, stream>>>(p);
}

// Round 12
// 11135.386 us; speedup vs baseline: 1.4036x; 1.4036x over previous
//
#include <hip/hip_runtime.h>
#include <math.h>

// ---------------- problem dims ----------------
#define VV 32000
#define HH 512
#define G3 1536   // 3*HH
#define TI 128    // encoder length
#define TO 64     // max decode length
#define NB 5      // beam width
#define NEGF (-1000000000.0f)
#define NTHR 256

struct Params {
  const int* seq;
  const int* sosp;
  const float *emb, *eWi, *eWh, *ebi, *ebh;
  const float *dWi, *dWh, *dbi, *dbh;
  const float *Wc, *bc, *Wout, *bout;
  int *cur_tok, *toks, *pars, *ptop_i;
  float *gi0, *eout, *h0b, *h1b, *dch, *cc, *ptop_v, *psum, *scores;
  float* out;
};

__device__ __forceinline__ float wredf(float v) {
#pragma unroll
  for (int o = 32; o; o >>= 1) v += __shfl_xor(v, o, 64);
  return v;
}

// ========== E0: gi0[t][row] = emb[seq[t]] . eWi0[row] + ebi0[row]; zero h ==========
__global__ void __launch_bounds__(NTHR) k_e0(Params p) {
  const int wg = blockIdx.x, tid = threadIdx.x;
  const int lane = tid & 63, wv = tid >> 6;
  if (wg == 0) {
    for (int i = tid; i < 2 * HH; i += NTHR) { p.h0b[i] = 0.f; p.h1b[i] = 0.f; }
  }
  for (int lr = wv; lr < 6; lr += 4) {
    int row = wg * 6 + lr;
    const float* W = p.eWi + (size_t)row * HH;
    float w0[8];
#pragma unroll
    for (int j = 0; j < 8; j++) w0[j] = W[j * 64 + lane];
    float bi = p.ebi[row];
    for (int t = 0; t < TI; t++) {
      const float* x = p.emb + (size_t)p.seq[t] * HH;
      float s = 0.f;
#pragma unroll
      for (int j = 0; j < 8; j++) s += w0[j] * x[j * 64 + lane];
      s = wredf(s);
      if (lane == 0) p.gi0[(size_t)t * G3 + row] = s + bi;
    }
  }
}

// ========== E1 step T: L0[T] (waves 0-1) overlapped with L1[T-1] (waves 2-3) ==========
__global__ void __launch_bounds__(NTHR) k_e1(Params p, int T) {
  const int wg = blockIdx.x, tid = threadIdx.x;
  const int lane = tid & 63, wv = tid >> 6;
  const int sIn = T & 1, sOut = sIn ^ 1;
  if (wv < 2) {
    if (T < TI) {
      const float* hprev = p.h0b + sIn * HH;
      float hv[8];
#pragma unroll
      for (int j = 0; j < 8; j++) hv[j] = hprev[j * 64 + lane];
#pragma unroll
      for (int uu = 0; uu < 4; uu++) {
        int u = wg * 8 + wv * 4 + uu;
        float g[3];
#pragma unroll
        for (int gg = 0; gg < 3; gg++) {
          const float* W = p.eWh + (size_t)(gg * HH + u) * HH;
          float s = 0.f;
#pragma unroll
          for (int j = 0; j < 8; j++) s += W[j * 64 + lane] * hv[j];
          g[gg] = wredf(s);
        }
        if (lane == 0) {
          const float* gr = p.gi0 + (size_t)T * G3;
          float ir = gr[u], iz = gr[HH + u], inn = gr[2 * HH + u];
          float hr = g[0] + p.ebh[u], hz = g[1] + p.ebh[HH + u], hn = g[2] + p.ebh[2 * HH + u];
          float r = 1.f / (1.f + expf(-(ir + hr)));
          float z = 1.f / (1.f + expf(-(iz + hz)));
          float n = tanhf(inn + r * hn);
          p.h0b[sOut * HH + u] = (1.f - z) * n + z * hprev[u];
        }
      }
    }
  } else {
    if (T >= 1) {
      const float* xsrc = p.h0b + sIn * HH;    // L0 output of step T-1
      const float* hprev = p.h1b + sOut * HH;  // h1 state after step T-2
      float xv[8], hv[8];
#pragma unroll
      for (int j = 0; j < 8; j++) { xv[j] = xsrc[j * 64 + lane]; hv[j] = hprev[j * 64 + lane]; }
#pragma unroll
      for (int uu = 0; uu < 4; uu++) {
        int u = wg * 8 + (wv - 2) * 4 + uu;
        float gi[3], gh[3];
#pragma unroll
        for (int gg = 0; gg < 3; gg++) {
          const float* Wi1 = p.eWi + (size_t)G3 * HH + (size_t)(gg * HH + u) * HH;
          const float* Wh1 = p.eWh + (size_t)G3 * HH + (size_t)(gg * HH + u) * HH;
          float si = 0.f, s2 = 0.f;
#pragma unroll
          for (int j = 0; j < 8; j++) { si += Wi1[j * 64 + lane] * xv[j]; s2 += Wh1[j * 64 + lane] * hv[j]; }
          gi[gg] = wredf(si);
          gh[gg] = wredf(s2);
        }
        if (lane == 0) {
          const float* bi = p.ebi + G3;
          const float* bh = p.ebh + G3;
          float ir = gi[0] + bi[u], iz = gi[1] + bi[HH + u], inn = gi[2] + bi[2 * HH + u];
          float hr = gh[0] + bh[u], hz = gh[1] + bh[HH + u], hn = gh[2] + bh[2 * HH + u];
          float r = 1.f / (1.f + expf(-(ir + hr)));
          float z = 1.f / (1.f + expf(-(iz + hz)));
          float n = tanhf(inn + r * hn);
          float hnew = (1.f - z) * n + z * hprev[u];
          p.h1b[sIn * HH + u] = hnew;
          p.eout[(size_t)(T - 1) * HH + u] = hnew;
        }
      }
    }
  }
}

// ========== D0: broadcast enc_hidden to beams, init tokens/scores ==========
__global__ void __launch_bounds__(NTHR) k_d0(Params p) {
  const int wg = blockIdx.x, tid = threadIdx.x;
  for (int i = tid + wg * NTHR; i < 2 * NB * HH; i += 64 * NTHR) {
    int l = i / (NB * HH);
    int rem = i - l * (NB * HH);
    int u = rem % HH;
    p.dch[(size_t)l * NB * HH + rem] = (l == 0) ? p.h0b[u] : p.h1b[u];
  }
  if (wg == 0 && tid < NB) {
    p.cur_tok[tid] = p.sosp[0];
    p.scores[tid] = (tid == 0) ? 0.f : NEGF;
  }
}

// ========== decoder GRU layer (64 WGs, 8 units each) ==========
template <int LAYER>
__global__ void __launch_bounds__(NTHR) k_gru(Params p, int t) {
  const int wg = blockIdx.x, tid = threadIdx.x;
  const int lane = tid & 63, wv = tid >> 6;
  const int ib = t & 1, ob = ib ^ 1;
  __shared__ float sm[2 * NB * HH + 48 * NB];
  float* sx = sm;                 // [NB][HH]
  float* sh = sm + NB * HH;       // [NB][HH]
  float* fres = sm + 2 * NB * HH; // [48][NB]

  for (int i = tid; i < NB * HH; i += NTHR) {
    int b = i / HH, u = i - b * HH;
    float xv;
    if (LAYER == 0) xv = p.emb[(size_t)p.cur_tok[b] * HH + u];
    else            xv = p.dch[((size_t)(ob * 2 + 0) * NB + b) * HH + u];
    sx[i] = xv;
    int pb = (t == 0) ? b : p.pars[(t - 1) * NB + b];
    sh[i] = p.dch[((size_t)(ib * 2 + LAYER) * NB + pb) * HH + u];
  }
  __syncthreads();
  const float* Wi = p.dWi + (size_t)LAYER * G3 * HH;
  const float* Wh = p.dWh + (size_t)LAYER * G3 * HH;
#pragma unroll
  for (int k = 0; k < 12; k++) {
    const int m_ = k % 6;                  // f%6 == k%6 since f = wv*12 + k
    const int f = wv * 12 + k;
    const int ul = f / 6;
    const int u = wg * 8 + ul;
    const float* W = (m_ >= 3 ? Wh : Wi) + (size_t)((m_ % 3) * HH + u) * HH;
    const float* vecb = (m_ >= 3) ? sh : sx;
    float wd[8];
#pragma unroll
    for (int j = 0; j < 8; j++) wd[j] = W[j * 64 + lane];
    float a0 = 0.f, a1 = 0.f, a2 = 0.f, a3 = 0.f, a4 = 0.f;
#pragma unroll
    for (int j = 0; j < 8; j++) {
      float wj = wd[j];
      int o = j * 64 + lane;
      a0 += wj * vecb[0 * HH + o];
      a1 += wj * vecb[1 * HH + o];
      a2 += wj * vecb[2 * HH + o];
      a3 += wj * vecb[3 * HH + o];
      a4 += wj * vecb[4 * HH + o];
    }
    float r0 = wredf(a0), r1 = wredf(a1), r2 = wredf(a2), r3 = wredf(a3), r4 = wredf(a4);
    if (lane == 0) {
      fres[f * NB + 0] = r0; fres[f * NB + 1] = r1; fres[f * NB + 2] = r2;
      fres[f * NB + 3] = r3; fres[f * NB + 4] = r4;
    }
  }
  __syncthreads();
  if (tid < 8 * NB) {
    int ul = tid / NB, b = tid - ul * NB;
    int u = wg * 8 + ul;
    const float* bi = p.dbi + LAYER * G3;
    const float* bh = p.dbh + LAYER * G3;
    float ir = fres[(ul * 6 + 0) * NB + b] + bi[u];
    float iz = fres[(ul * 6 + 1) * NB + b] + bi[HH + u];
    float inn = fres[(ul * 6 + 2) * NB + b] + bi[2 * HH + u];
    float hr = fres[(ul * 6 + 3) * NB + b] + bh[u];
    float hz = fres[(ul * 6 + 4) * NB + b] + bh[HH + u];
    float hn = fres[(ul * 6 + 5) * NB + b] + bh[2 * HH + u];
    float hp = sh[b * HH + u];
    float r = 1.f / (1.f + expf(-(ir + hr)));
    float z = 1.f / (1.f + expf(-(iz + hz)));
    float n = tanhf(inn + r * hn);
    p.dch[((size_t)(ob * 2 + LAYER) * NB + b) * HH + u] = (1.f - z) * n + z * hp;
  }
}

// ========== PA: attention + ctx + Wc + tanh (40 WGs, 8 per beam) ==========
__global__ void __launch_bounds__(NTHR) k_pa(Params p, int t) {
  const int wg = blockIdx.x, tid = threadIdx.x;
  const int lane = tid & 63, wv = tid >> 6;
  const int ob = (t & 1) ^ 1;
  __shared__ float sm[3200];
  const int b = wg / 8, q = wg % 8;
  float* srnn = sm;            // 512
  float* sp = sm + 512;        // 128
  float* cpart = sm + 640;     // [4][512]
  float* sctx = sm + 2688;     // 512
  for (int i = tid; i < HH; i += NTHR)
    srnn[i] = p.dch[((size_t)(ob * 2 + 1) * NB + b) * HH + i];
  __syncthreads();
  for (int j = wv; j < TI; j += 4) {
    const float* E = p.eout + (size_t)j * HH;
    float s = 0.f;
#pragma unroll
    for (int k2 = 0; k2 < 8; k2++) s += srnn[k2 * 64 + lane] * E[k2 * 64 + lane];
    s = wredf(s);
    if (lane == 0) sp[j] = s;
  }
  __syncthreads();
  if (wv == 0) {
    float v0 = sp[lane], v1 = sp[64 + lane];
    float mx = fmaxf(v0, v1);
#pragma unroll
    for (int o = 32; o; o >>= 1) mx = fmaxf(mx, __shfl_xor(mx, o, 64));
    float e0 = expf(v0 - mx), e1 = expf(v1 - mx);
    float ss = wredf(e0 + e1);
    sp[lane] = e0 / ss;
    sp[64 + lane] = e1 / ss;
  }
  __syncthreads();
  {  // coalesced ctx: per-wave partials over strided j, combine in LDS
    float cp[8];
#pragma unroll
    for (int k2 = 0; k2 < 8; k2++) cp[k2] = 0.f;
    for (int j = wv; j < TI; j += 4) {
      float spj = sp[j];
      const float* E = p.eout + (size_t)j * HH;
#pragma unroll
      for (int k2 = 0; k2 < 8; k2++) cp[k2] += spj * E[k2 * 64 + lane];
    }
#pragma unroll
    for (int k2 = 0; k2 < 8; k2++) cpart[wv * HH + k2 * 64 + lane] = cp[k2];
  }
  __syncthreads();
  for (int i = tid; i < HH; i += NTHR)
    sctx[i] = ((cpart[0 * HH + i] + cpart[1 * HH + i]) + cpart[2 * HH + i]) + cpart[3 * HH + i];
  __syncthreads();
  for (int k = wv; k < 64; k += 4) {
    int u = q * 64 + k;
    const float* W = p.Wc + (size_t)u * (2 * HH);
    float s0 = 0.f, s1 = 0.f;
#pragma unroll
    for (int j = 0; j < 8; j++) {
      int o = j * 64 + lane;
      s0 += W[o] * srnn[o];
      s1 += W[HH + o] * sctx[o];
    }
    float r0 = wredf(s0), r1 = wredf(s1);
    if (lane == 0) p.cc[b * HH + u] = tanhf(r0 + r1 + p.bc[u]);
  }
}

// ========== P5: logits chunk (125 rows/WG) + per-beam partial top5 + exp-sum ==========
__global__ void __launch_bounds__(NTHR) k_p5(Params p, int t) {
  const int wg = blockIdx.x, tid = threadIdx.x;
  const int lane = tid & 63, wv = tid >> 6;
  __shared__ float sm[NB * HH + NB * 125];
  float* scc = sm;            // [NB][HH]
  float* slg = sm + NB * HH;  // [NB][125]
  for (int i = tid; i < NB * HH; i += NTHR) scc[i] = p.cc[i];
  __syncthreads();
  const int vbase = wg * 125;
  for (int r = wv; r < 125; r += 4) {
    int v = vbase + r;
    const float* W = p.Wout + (size_t)v * HH;
    float w0[8];
#pragma unroll
    for (int j = 0; j < 8; j++) w0[j] = W[j * 64 + lane];
    float a0 = 0.f, a1 = 0.f, a2 = 0.f, a3 = 0.f, a4 = 0.f;
#pragma unroll
    for (int j = 0; j < 8; j++) {
      float wj = w0[j];
      int o = j * 64 + lane;
      a0 += wj * scc[0 * HH + o];
      a1 += wj * scc[1 * HH + o];
      a2 += wj * scc[2 * HH + o];
      a3 += wj * scc[3 * HH + o];
      a4 += wj * scc[4 * HH + o];
    }
    float r0 = wredf(a0), r1 = wredf(a1), r2 = wredf(a2), r3 = wredf(a3), r4 = wredf(a4);
    if (lane == 0) {
      float bo = p.bout[v];
      slg[0 * 125 + r] = r0 + bo;
      slg[1 * 125 + r] = r1 + bo;
      slg[2 * 125 + r] = r2 + bo;
      slg[3 * 125 + r] = r3 + bo;
      slg[4 * 125 + r] = r4 + bo;
    }
  }
  __syncthreads();
  if (wv == 0) {
    for (int b = 0; b < NB; b++) {
      float s0 = (lane < 125) ? expf(slg[b * 125 + lane]) : 0.f;
      float s1 = (lane + 64 < 125) ? expf(slg[b * 125 + lane + 64]) : 0.f;
      float ss = wredf(s0 + s1);
      if (lane == 0) p.psum[wg * NB + b] = ss;
    }
  } else if (wv == 1 && lane < NB) {
    int b = lane;
    float bv[5]; int bidx[5];
#pragma unroll
    for (int k = 0; k < 5; k++) { bv[k] = -INFINITY; bidx[k] = 0x7fffffff; }
    for (int r = 0; r < 125; r++) {
      float v = slg[b * 125 + r];
      if (v > bv[4]) {  // strict >: equal values keep earlier (lower) index
        int k = 4;
        while (k > 0 && v > bv[k - 1]) { bv[k] = bv[k - 1]; bidx[k] = bidx[k - 1]; k--; }
        bv[k] = v; bidx[k] = vbase + r;
      }
    }
#pragma unroll
    for (int k = 0; k < 5; k++) {
      p.ptop_v[(wg * NB + b) * 5 + k] = bv[k];
      p.ptop_i[(wg * NB + b) * 5 + k] = bidx[k];
    }
  }
}

// ========== P6: merge (1 WG): lse, global top5/beam, 25-cand top5, bookkeeping ==========
__global__ void __launch_bounds__(NTHR) k_p6(Params p, int t) {
  const int tid = threadIdx.x;
  const int lane = tid & 63, wv = tid >> 6;
  __shared__ float sm[2664];
  float* sval = sm;                  // [256][5]
  int* sidx = (int*)(sm + 1280);     // [256][5]
  float* sls = sm + 2560;            // [5]
  float* smv = sm + 2576;            // [5][5]
  int* smi = (int*)(sm + 2608);      // [5][5]
  if (wv == 0) {
    for (int b = 0; b < NB; b++) {
      float q0 = p.psum[(lane + 0) * NB + b];
      float q1 = p.psum[(lane + 64) * NB + b];
      float q2 = p.psum[(lane + 128) * NB + b];
      float q3 = p.psum[(lane + 192) * NB + b];
      float s = wredf((q0 + q1) + (q2 + q3));
      if (lane == 0) sls[b] = logf(s);
    }
  }
  __syncthreads();
  for (int b = 0; b < NB; b++) {
#pragma unroll
    for (int k = 0; k < 5; k++) {
      sval[tid * 5 + k] = p.ptop_v[(tid * NB + b) * 5 + k];
      sidx[tid * 5 + k] = p.ptop_i[(tid * NB + b) * 5 + k];
    }
    __syncthreads();
    for (int n = 128; n >= 1; n >>= 1) {
      if (tid < n) {
        float av[5], bv[5], ov[5];
        int ai[5], bi2[5], oi[5];
#pragma unroll
        for (int k = 0; k < 5; k++) {
          av[k] = sval[tid * 5 + k]; ai[k] = sidx[tid * 5 + k];
          bv[k] = sval[(tid + n) * 5 + k]; bi2[k] = sidx[(tid + n) * 5 + k];
        }
        int i = 0, j = 0;
#pragma unroll
        for (int k = 0; k < 5; k++) {
          bool ta = (av[i] > bv[j]) || (av[i] == bv[j] && ai[i] < bi2[j]);
          if (ta) { ov[k] = av[i]; oi[k] = ai[i]; i++; }
          else { ov[k] = bv[j]; oi[k] = bi2[j]; j++; }
        }
#pragma unroll
        for (int k = 0; k < 5; k++) { sval[tid * 5 + k] = ov[k]; sidx[tid * 5 + k] = oi[k]; }
      }
      __syncthreads();
    }
    if (tid == 0) {
#pragma unroll
      for (int k = 0; k < 5; k++) { smv[b * 5 + k] = sval[k]; smi[b * 5 + k] = sidx[k]; }
    }
    __syncthreads();
  }
  if (tid == 0) {
    float cand[25]; int ctok[25];
    for (int b = 0; b < NB; b++) {
      float sb = p.scores[b], lb = sls[b];
#pragma unroll
      for (int k = 0; k < 5; k++) {
        cand[b * 5 + k] = sb + (smv[b * 5 + k] - lb);
        ctok[b * 5 + k] = smi[b * 5 + k];
      }
    }
    float s5[5]; int f5[5];
#pragma unroll
    for (int k = 0; k < 5; k++) { s5[k] = -INFINITY; f5[k] = 0x7fffffff; }
    for (int f = 0; f < 25; f++) {
      float v = cand[f];
      if (v > s5[4]) {
        int k = 4;
        while (k > 0 && v > s5[k - 1]) { s5[k] = s5[k - 1]; f5[k] = f5[k - 1]; k--; }
        s5[k] = v; f5[k] = f;
      }
    }
    for (int j2 = 0; j2 < 5; j2++) {
      int fl = f5[j2];
      p.pars[t * NB + j2] = fl / 5;
      p.toks[t * NB + j2] = ctok[fl];
      p.cur_tok[j2] = ctok[fl];
    }
    for (int j2 = 0; j2 < 5; j2++) p.scores[j2] = s5[j2];
  }
}

// ========== F: backtrack and write output (seq as float, then score) ==========
__global__ void k_fin(Params p) {
  if (threadIdx.x == 0 && blockIdx.x == 0) {
    int best = 0;
    float bvv = p.scores[0];
    for (int j = 1; j < NB; j++)
      if (p.scores[j] > bvv) { bvv = p.scores[j]; best = j; }
    int beam = best;
    for (int tt = TO - 1; tt >= 0; tt--) {
      p.out[tt] = (float)p.toks[tt * NB + beam];
      beam = p.pars[tt * NB + beam];
    }
    p.out[TO] = bvv;
  }
}

extern "C" void kernel_launch(void* const* d_in, const int* in_sizes, int n_in,
                              void* d_out, int out_size, void* d_ws, size_t ws_size,
                              hipStream_t stream) {
  (void)in_sizes; (void)n_in; (void)out_size; (void)ws_size;
  Params p;
  p.seq  = (const int*)d_in[0];
  p.sosp = (const int*)d_in[3];
  p.emb  = (const float*)d_in[4];
  p.eWi  = (const float*)d_in[5];
  p.eWh  = (const float*)d_in[6];
  p.ebi  = (const float*)d_in[7];
  p.ebh  = (const float*)d_in[8];
  p.dWi  = (const float*)d_in[9];
  p.dWh  = (const float*)d_in[10];
  p.dbi  = (const float*)d_in[11];
  p.dbh  = (const float*)d_in[12];
  p.Wc   = (const float*)d_in[13];
  p.bc   = (const float*)d_in[14];
  p.Wout = (const float*)d_in[15];
  p.bout = (const float*)d_in[16];

  char* w = (char*)d_ws;
  size_t off = 0;
  auto alloc = [&](size_t words) -> char* {
    char* r = w + off;
    off += words * 4;
    off = (off + 255) & ~(size_t)255;
    return r;
  };
  p.cur_tok = (int*)alloc(8);
  p.toks    = (int*)alloc(TO * NB);
  p.pars    = (int*)alloc(TO * NB);
  p.ptop_i  = (int*)alloc(256 * NB * 5);
  p.gi0     = (float*)alloc((size_t)TI * G3);
  p.eout    = (float*)alloc((size_t)TI * HH);
  p.h0b     = (float*)alloc(2 * HH);
  p.h1b     = (float*)alloc(2 * HH);
  p.dch     = (float*)alloc(2 * 2 * NB * HH);
  p.cc      = (float*)alloc(NB * HH);
  p.ptop_v  = (float*)alloc(256 * NB * 5);
  p.psum    = (float*)alloc(256 * NB);
  p.scores  = (float*)alloc(8);
  p.out     = (float*)d_out;

  // Multi-kernel pipeline: stream order + kernel-boundary cache semantics
  // replace ALL in-kernel cross-WG synchronization (r7-r11's ~30us/leg floor).
  k_e0<<<dim3(256), dim3(NTHR), 0, stream>>>(p);
  for (int T = 0; T <= TI; T++)
    k_e1<<<dim3(64), dim3(NTHR), 0, stream>>>(p, T);
  k_d0<<<dim3(64), dim3(NTHR), 0, stream>>>(p);
  for (int t = 0; t < TO; t++) {
    k_gru<0><<<dim3(64), dim3(NTHR), 0, stream>>>(p, t);
    k_gru<1><<<dim3(64), dim3(NTHR), 0, stream>>>(p, t);
    k_pa<<<dim3(40), dim3(NTHR), 0, stream>>>(p, t);
    k_p5<<<dim3(256), dim3(NTHR), 0, stream>>>(p, t);
    k_p6<<<dim3(1), dim3(NTHR), 0, stream>>>(p, t);
  }
  k_fin<<<dim3(1), dim3(64), 0, stream>>>(p);
}

// Round 13
// 9845.873 us; speedup vs baseline: 1.5875x; 1.1310x over previous
//
#include <hip/hip_runtime.h>
#include <math.h>

// ---------------- problem dims ----------------
#define VV 32000
#define HH 512
#define G3 1536   // 3*HH
#define TI 128    // encoder length
#define TO 64     // max decode length
#define NB 5      // beam width
#define NEGF (-1000000000.0f)
#define NTHR 256
#define LSTR 32   // words per counter/flag line (128B)

struct Params {
  const int* seq;
  const int* sosp;
  const float *emb, *eWi, *eWh, *ebi, *ebh;
  const float *dWi, *dWh, *dbi, *dbh;
  const float *Wc, *bc, *Wout, *bout;
  unsigned* bar;
  int *cur_tok, *toks, *pars, *ptop_i;
  float *gi0, *eout, *h0b, *h1b, *dch, *cc, *ptop_v, *psum, *scores;
  float* out;
};

// relaxed agent-scope (coherence-point) ops for INTRA-kernel cross-WG data
__device__ __forceinline__ float cldf(const float* p) {
  return __hip_atomic_load(p, __ATOMIC_RELAXED, __HIP_MEMORY_SCOPE_AGENT);
}
__device__ __forceinline__ void cstf(float* p, float v) {
  __hip_atomic_store(p, v, __ATOMIC_RELAXED, __HIP_MEMORY_SCOPE_AGENT);
}
__device__ __forceinline__ int cldi(const int* p) {
  return __hip_atomic_load(p, __ATOMIC_RELAXED, __HIP_MEMORY_SCOPE_AGENT);
}
__device__ __forceinline__ void csti(int* p, int v) {
  __hip_atomic_store(p, v, __ATOMIC_RELAXED, __HIP_MEMORY_SCOPE_AGENT);
}
__device__ __forceinline__ unsigned rldu(const unsigned* p) {
  return __hip_atomic_load(p, __ATOMIC_RELAXED, __HIP_MEMORY_SCOPE_AGENT);
}
typedef unsigned long long u64t;
union F2U { u64t u; float f[2]; };
__device__ __forceinline__ void cld2(float* d, const float* p) {
  F2U x; x.u = __hip_atomic_load((const u64t*)p, __ATOMIC_RELAXED, __HIP_MEMORY_SCOPE_AGENT);
  d[0] = x.f[0]; d[1] = x.f[1];
}
__device__ __forceinline__ void cst2(float* p, float a, float b) {
  F2U x; x.f[0] = a; x.f[1] = b;
  __hip_atomic_store((u64t*)p, x.u, __ATOMIC_RELAXED, __HIP_MEMORY_SCOPE_AGENT);
}

__device__ __forceinline__ void bar_arrive(unsigned* lines, int myline) {
  __syncthreads();  // all this WG's sc-stores vm-drained (at CP)
  if (threadIdx.x == 0)
    __hip_atomic_fetch_add(lines + myline * LSTR, 1u,
                           __ATOMIC_RELAXED, __HIP_MEMORY_SCOPE_AGENT);
}
template <int SLP>
__device__ __forceinline__ void bar_wait8(const unsigned* lines, unsigned tgt) {
  if (threadIdx.x < 64) {
    for (;;) {
      unsigned v = tgt;
      if (threadIdx.x < 8) v = rldu(lines + threadIdx.x * LSTR);
      if (__all(v >= tgt)) break;
      __builtin_amdgcn_s_sleep(SLP);
    }
  }
  __syncthreads();
}
__device__ __forceinline__ void bcast_store(unsigned* L, int NL, unsigned tok) {
  asm volatile("s_waitcnt vmcnt(0)" ::: "memory");
  for (int i = 0; i < NL; i++)
    __hip_atomic_store(L + i * LSTR, tok, __ATOMIC_RELAXED, __HIP_MEMORY_SCOPE_AGENT);
}
template <int SLP>
__device__ __forceinline__ void leaf_wait(const unsigned* L, int grp, unsigned tok) {
  if (threadIdx.x == 0) {
    while (rldu(L + grp * LSTR) < tok) __builtin_amdgcn_s_sleep(SLP);
  }
  __syncthreads();
}

__device__ __forceinline__ float wredf(float v) {
#pragma unroll
  for (int o = 32; o; o >>= 1) v += __shfl_xor(v, o, 64);
  return v;
}

// ========== E0: gi0[t][row] = emb[seq[t]] . eWi0[row] + ebi0[row]; zero h ==========
__global__ void __launch_bounds__(NTHR) k_e0(Params p) {
  const int wg = blockIdx.x, tid = threadIdx.x;
  const int lane = tid & 63, wv = tid >> 6;
  if (wg == 0) {
    for (int i = tid; i < 2 * HH; i += NTHR) { cstf(&p.h0b[i], 0.f); cstf(&p.h1b[i], 0.f); }
  }
  for (int lr = wv; lr < 6; lr += 4) {
    int row = wg * 6 + lr;
    const float* W = p.eWi + (size_t)row * HH;
    float w0[8];
#pragma unroll
    for (int j = 0; j < 8; j++) w0[j] = W[j * 64 + lane];
    float bi = p.ebi[row];
    for (int t = 0; t < TI; t++) {
      const float* x = p.emb + (size_t)p.seq[t] * HH;
      float s = 0.f;
#pragma unroll
      for (int j = 0; j < 8; j++) s += w0[j] * x[j * 64 + lane];
      s = wredf(s);
      if (lane == 0) p.gi0[(size_t)t * G3 + row] = s + bi;
    }
  }
}

// one encoder diagonal step (L0[T] on waves 0-1, L1[T-1] on waves 2-3);
// h0b/h1b via sc ops (intra-node visibility), gi0 plain cached (immutable).
__device__ void enc_step(const Params& p, int T, int wg, int lane, int wv) {
  const int sIn = T & 1, sOut = sIn ^ 1;
  if (wv < 2) {
    if (T < TI) {
      float hv[8];
#pragma unroll
      for (int j = 0; j < 8; j++) hv[j] = cldf(&p.h0b[sIn * HH + j * 64 + lane]);
#pragma unroll
      for (int uu = 0; uu < 4; uu++) {
        int u = wg * 8 + wv * 4 + uu;
        float g[3];
#pragma unroll
        for (int gg = 0; gg < 3; gg++) {
          const float* W = p.eWh + (size_t)(gg * HH + u) * HH;
          float s = 0.f;
#pragma unroll
          for (int j = 0; j < 8; j++) s += W[j * 64 + lane] * hv[j];
          g[gg] = wredf(s);
        }
        if (lane == 0) {
          const float* gr = p.gi0 + (size_t)T * G3;
          float ir = gr[u], iz = gr[HH + u], inn = gr[2 * HH + u];
          float hr = g[0] + p.ebh[u], hz = g[1] + p.ebh[HH + u], hn = g[2] + p.ebh[2 * HH + u];
          float r = 1.f / (1.f + expf(-(ir + hr)));
          float z = 1.f / (1.f + expf(-(iz + hz)));
          float n = tanhf(inn + r * hn);
          float hp = cldf(&p.h0b[sIn * HH + u]);
          cstf(&p.h0b[sOut * HH + u], (1.f - z) * n + z * hp);
        }
      }
    }
  } else {
    if (T >= 1) {
      float xv[8], hv[8];
#pragma unroll
      for (int j = 0; j < 8; j++) {
        xv[j] = cldf(&p.h0b[sIn * HH + j * 64 + lane]);
        hv[j] = cldf(&p.h1b[sOut * HH + j * 64 + lane]);
      }
#pragma unroll
      for (int uu = 0; uu < 4; uu++) {
        int u = wg * 8 + (wv - 2) * 4 + uu;
        float gi[3], gh[3];
#pragma unroll
        for (int gg = 0; gg < 3; gg++) {
          const float* Wi1 = p.eWi + (size_t)G3 * HH + (size_t)(gg * HH + u) * HH;
          const float* Wh1 = p.eWh + (size_t)G3 * HH + (size_t)(gg * HH + u) * HH;
          float si = 0.f, s2 = 0.f;
#pragma unroll
          for (int j = 0; j < 8; j++) { si += Wi1[j * 64 + lane] * xv[j]; s2 += Wh1[j * 64 + lane] * hv[j]; }
          gi[gg] = wredf(si);
          gh[gg] = wredf(s2);
        }
        if (lane == 0) {
          const float* bi = p.ebi + G3;
          const float* bh = p.ebh + G3;
          float ir = gi[0] + bi[u], iz = gi[1] + bi[HH + u], inn = gi[2] + bi[2 * HH + u];
          float hr = gh[0] + bh[u], hz = gh[1] + bh[HH + u], hn = gh[2] + bh[2 * HH + u];
          float r = 1.f / (1.f + expf(-(ir + hr)));
          float z = 1.f / (1.f + expf(-(iz + hz)));
          float n = tanhf(inn + r * hn);
          float hp = cldf(&p.h1b[sOut * HH + u]);
          float hnew = (1.f - z) * n + z * hp;
          cstf(&p.h1b[sIn * HH + u], hnew);
          p.eout[(size_t)(T - 1) * HH + u] = hnew;  // plain: flushed at node end
        }
      }
    }
  }
}

// node k: diagonal steps T=2k and T=2k+1 with one internal leg
__global__ void __launch_bounds__(NTHR) k_e1x2(Params p, int k) {
  const int wg = blockIdx.x, tid = threadIdx.x;
  const int lane = tid & 63, wv = tid >> 6;
  unsigned* ceA = p.bar + 0 * LSTR;
  enc_step(p, 2 * k, wg, lane, wv);
  if (2 * k + 1 <= TI) {
    bar_arrive(ceA, wg & 7);
    bar_wait8<2>(ceA, (unsigned)(8 * (k + 1)));
    enc_step(p, 2 * k + 1, wg, lane, wv);
  }
}

// ========== D0: broadcast enc_hidden to beams, init tokens/scores ==========
__global__ void __launch_bounds__(NTHR) k_d0(Params p) {
  const int wg = blockIdx.x, tid = threadIdx.x;
  for (int i = tid + wg * NTHR; i < 2 * NB * HH; i += 64 * NTHR) {
    int l = i / (NB * HH);
    int rem = i - l * (NB * HH);
    int u = rem % HH;
    p.dch[(size_t)l * NB * HH + rem] = (l == 0) ? cldf(&p.h0b[u]) : cldf(&p.h1b[u]);
  }
  if (wg == 0 && tid < NB) {
    p.cur_tok[tid] = p.sosp[0];
    p.scores[tid] = (tid == 0) ? 0.f : NEGF;
  }
}

// one decoder GRU layer body (64 WGs, 8 units each); dch via sc ops
template <int LAYER>
__device__ void gru_body(const Params& p, float* sm, int t, int ib, int ob,
                         int wg, int tid, int lane, int wv) {
  float* sx = sm;                 // [NB][HH]
  float* sh = sm + NB * HH;       // [NB][HH]
  float* fres = sm + 2 * NB * HH; // [48][NB]
  int ct[NB], pr[NB];
#pragma unroll
  for (int b = 0; b < NB; b++) {
    ct[b] = (LAYER == 0) ? cldi(&p.cur_tok[b]) : 0;
    pr[b] = (t == 0) ? b : cldi(&p.pars[(t - 1) * NB + b]);
  }
  for (int i = tid; i < NB * (HH / 2); i += NTHR) {
    int b = i >> 8, c = (i & 255) << 1;
    float x2[2], h2[2];
    if (LAYER == 0) {
      const float* e = p.emb + (size_t)ct[b] * HH + c;
      x2[0] = e[0]; x2[1] = e[1];
    } else {
      cld2(x2, &p.dch[((size_t)(ob * 2 + 0) * NB + b) * HH + c]);
    }
    cld2(h2, &p.dch[((size_t)(ib * 2 + LAYER) * NB + pr[b]) * HH + c]);
    sx[b * HH + c] = x2[0]; sx[b * HH + c + 1] = x2[1];
    sh[b * HH + c] = h2[0]; sh[b * HH + c + 1] = h2[1];
  }
  __syncthreads();
  const float* Wi = p.dWi + (size_t)LAYER * G3 * HH;
  const float* Wh = p.dWh + (size_t)LAYER * G3 * HH;
#pragma unroll
  for (int k = 0; k < 12; k++) {
    const int m_ = k % 6;
    const int f = wv * 12 + k;
    const int ul = f / 6;
    const int u = wg * 8 + ul;
    const float* W = (m_ >= 3 ? Wh : Wi) + (size_t)((m_ % 3) * HH + u) * HH;
    const float* vecb = (m_ >= 3) ? sh : sx;
    float wd[8];
#pragma unroll
    for (int j = 0; j < 8; j++) wd[j] = W[j * 64 + lane];
    float a0 = 0.f, a1 = 0.f, a2 = 0.f, a3 = 0.f, a4 = 0.f;
#pragma unroll
    for (int j = 0; j < 8; j++) {
      float wj = wd[j];
      int o = j * 64 + lane;
      a0 += wj * vecb[0 * HH + o];
      a1 += wj * vecb[1 * HH + o];
      a2 += wj * vecb[2 * HH + o];
      a3 += wj * vecb[3 * HH + o];
      a4 += wj * vecb[4 * HH + o];
    }
    float r0 = wredf(a0), r1 = wredf(a1), r2 = wredf(a2), r3 = wredf(a3), r4 = wredf(a4);
    if (lane == 0) {
      fres[f * NB + 0] = r0; fres[f * NB + 1] = r1; fres[f * NB + 2] = r2;
      fres[f * NB + 3] = r3; fres[f * NB + 4] = r4;
    }
  }
  __syncthreads();
  if (tid < 8 * NB) {
    int ul = tid / NB, b = tid - ul * NB;
    int u = wg * 8 + ul;
    const float* bi = p.dbi + LAYER * G3;
    const float* bh = p.dbh + LAYER * G3;
    float ir = fres[(ul * 6 + 0) * NB + b] + bi[u];
    float iz = fres[(ul * 6 + 1) * NB + b] + bi[HH + u];
    float inn = fres[(ul * 6 + 2) * NB + b] + bi[2 * HH + u];
    float hr = fres[(ul * 6 + 3) * NB + b] + bh[u];
    float hz = fres[(ul * 6 + 4) * NB + b] + bh[HH + u];
    float hn = fres[(ul * 6 + 5) * NB + b] + bh[2 * HH + u];
    float hp = sh[b * HH + u];
    float r = 1.f / (1.f + expf(-(ir + hr)));
    float z = 1.f / (1.f + expf(-(iz + hz)));
    float n = tanhf(inn + r * hn);
    cstf(&p.dch[((size_t)(ob * 2 + LAYER) * NB + b) * HH + u], (1.f - z) * n + z * hp);
  }
  __syncthreads();
}

// fused GRU0 + leg + GRU1 (64 WGs)
__global__ void __launch_bounds__(NTHR) k_gru2(Params p, int t) {
  const int wg = blockIdx.x, tid = threadIdx.x;
  const int lane = tid & 63, wv = tid >> 6;
  const int ib = t & 1, ob = ib ^ 1;
  __shared__ float sm[2 * NB * HH + 48 * NB];
  unsigned* gruA = p.bar + 8 * LSTR;
  gru_body<0>(p, sm, t, ib, ob, wg, tid, lane, wv);
  bar_arrive(gruA, wg & 7);
  bar_wait8<2>(gruA, (unsigned)(8 * (t + 1)));
  gru_body<1>(p, sm, t, ib, ob, wg, tid, lane, wv);
}

// fused PA (wg<40) + leg + P5 (256 WGs) + last-man P6 merge (+final backtrack)
__global__ void __launch_bounds__(NTHR) k_pa56(Params p, int t) {
  const int wg = blockIdx.x, tid = threadIdx.x;
  const int lane = tid & 63, wv = tid >> 6;
  const int ob = (t & 1) ^ 1;
  __shared__ float sm[3200];
  __shared__ unsigned s_mrg;
  unsigned* paA = p.bar + 16 * LSTR;  // 8
  unsigned* paF = p.bar + 24 * LSTR;  // 1
  unsigned* paL = p.bar + 32 * LSTR;  // 16
  unsigned* c5A = p.bar + 48 * LSTR;  // 8
  unsigned* c5F = p.bar + 56 * LSTR;  // 1

  if (wg < 40) {
    const int b = wg / 8, q = wg % 8;
    float* srnn = sm;            // 512
    float* sp = sm + 512;        // 128
    float* cpart = sm + 640;     // [4][512]
    float* sctx = sm + 2688;     // 512
    for (int i = tid; i < HH; i += NTHR)
      srnn[i] = cldf(&p.dch[((size_t)(ob * 2 + 1) * NB + b) * HH + i]);
    __syncthreads();
    for (int j = wv; j < TI; j += 4) {
      const float* E = p.eout + (size_t)j * HH;  // plain cached (immutable)
      float s = 0.f;
#pragma unroll
      for (int k2 = 0; k2 < 8; k2++) s += srnn[k2 * 64 + lane] * E[k2 * 64 + lane];
      s = wredf(s);
      if (lane == 0) sp[j] = s;
    }
    __syncthreads();
    if (wv == 0) {
      float v0 = sp[lane], v1 = sp[64 + lane];
      float mx = fmaxf(v0, v1);
#pragma unroll
      for (int o = 32; o; o >>= 1) mx = fmaxf(mx, __shfl_xor(mx, o, 64));
      float e0 = expf(v0 - mx), e1 = expf(v1 - mx);
      float ss = wredf(e0 + e1);
      sp[lane] = e0 / ss;
      sp[64 + lane] = e1 / ss;
    }
    __syncthreads();
    {
      float cp[8];
#pragma unroll
      for (int k2 = 0; k2 < 8; k2++) cp[k2] = 0.f;
      for (int j = wv; j < TI; j += 4) {
        float spj = sp[j];
        const float* E = p.eout + (size_t)j * HH;
#pragma unroll
        for (int k2 = 0; k2 < 8; k2++) cp[k2] += spj * E[k2 * 64 + lane];
      }
#pragma unroll
      for (int k2 = 0; k2 < 8; k2++) cpart[wv * HH + k2 * 64 + lane] = cp[k2];
    }
    __syncthreads();
    for (int i = tid; i < HH; i += NTHR)
      sctx[i] = ((cpart[0 * HH + i] + cpart[1 * HH + i]) + cpart[2 * HH + i]) + cpart[3 * HH + i];
    __syncthreads();
    for (int k = wv; k < 64; k += 4) {
      int u = q * 64 + k;
      const float* W = p.Wc + (size_t)u * (2 * HH);
      float s0 = 0.f, s1 = 0.f;
#pragma unroll
      for (int j = 0; j < 8; j++) {
        int o = j * 64 + lane;
        s0 += W[o] * srnn[o];
        s1 += W[HH + o] * sctx[o];
      }
      float r0 = wredf(s0), r1 = wredf(s1);
      if (lane == 0) cstf(&p.cc[b * HH + u], tanhf(r0 + r1 + p.bc[u]));
    }
    // last-man over PA -> bcast paL
    __syncthreads();
    if (tid == 0) {
      unsigned o1 = __hip_atomic_fetch_add(paA + (wg & 7) * LSTR, 1u,
                                           __ATOMIC_RELAXED, __HIP_MEMORY_SCOPE_AGENT);
      if (o1 == (unsigned)(5 * (t + 1) - 1)) {
        unsigned o2 = __hip_atomic_fetch_add(paF, 1u,
                                             __ATOMIC_RELAXED, __HIP_MEMORY_SCOPE_AGENT);
        if (o2 == (unsigned)(8 * (t + 1) - 1))
          bcast_store(paL, 16, (unsigned)(t + 1));
      }
    }
  }
  leaf_wait<4>(paL, wg >> 4, (unsigned)(t + 1));

  // ---- P5: logits chunk (125 rows/WG) + per-beam partial top5 + exp-sum ----
  {
    float* scc = sm;            // [NB][HH]
    float* slg = sm + NB * HH;  // [NB][125]
    for (int i = tid; i < NB * (HH / 2); i += NTHR) {
      int b = i >> 8, c = (i & 255) << 1;
      float c2v[2];
      cld2(c2v, &p.cc[b * HH + c]);
      scc[b * HH + c] = c2v[0]; scc[b * HH + c + 1] = c2v[1];
    }
    __syncthreads();
    const int vbase = wg * 125;
    for (int r = wv; r < 125; r += 4) {
      int v = vbase + r;
      const float* W = p.Wout + (size_t)v * HH;
      float w0[8];
#pragma unroll
      for (int j = 0; j < 8; j++) w0[j] = W[j * 64 + lane];
      float a0 = 0.f, a1 = 0.f, a2 = 0.f, a3 = 0.f, a4 = 0.f;
#pragma unroll
      for (int j = 0; j < 8; j++) {
        float wj = w0[j];
        int o = j * 64 + lane;
        a0 += wj * scc[0 * HH + o];
        a1 += wj * scc[1 * HH + o];
        a2 += wj * scc[2 * HH + o];
        a3 += wj * scc[3 * HH + o];
        a4 += wj * scc[4 * HH + o];
      }
      float r0 = wredf(a0), r1 = wredf(a1), r2 = wredf(a2), r3 = wredf(a3), r4 = wredf(a4);
      if (lane == 0) {
        float bo = p.bout[v];
        slg[0 * 125 + r] = r0 + bo;
        slg[1 * 125 + r] = r1 + bo;
        slg[2 * 125 + r] = r2 + bo;
        slg[3 * 125 + r] = r3 + bo;
        slg[4 * 125 + r] = r4 + bo;
      }
    }
    __syncthreads();
    if (wv == 0) {
      for (int b = 0; b < NB; b++) {
        float s0 = (lane < 125) ? expf(slg[b * 125 + lane]) : 0.f;
        float s1 = (lane + 64 < 125) ? expf(slg[b * 125 + lane + 64]) : 0.f;
        float ss = wredf(s0 + s1);
        if (lane == 0) cstf(&p.psum[wg * NB + b], ss);
      }
    } else if (wv == 1 && lane < NB) {
      int b = lane;
      float bv[5]; int bidx[5];
#pragma unroll
      for (int k = 0; k < 5; k++) { bv[k] = -INFINITY; bidx[k] = 0x7fffffff; }
      for (int r = 0; r < 125; r++) {
        float v = slg[b * 125 + r];
        if (v > bv[4]) {
          int k = 4;
          while (k > 0 && v > bv[k - 1]) { bv[k] = bv[k - 1]; bidx[k] = bidx[k - 1]; k--; }
          bv[k] = v; bidx[k] = vbase + r;
        }
      }
#pragma unroll
      for (int k = 0; k < 5; k++) {
        cstf(&p.ptop_v[(wg * NB + b) * 5 + k], bv[k]);
        csti(&p.ptop_i[(wg * NB + b) * 5 + k], bidx[k]);
      }
    }
  }

  // ---- last-man selection: final P5 arriver performs the merge ----
  __syncthreads();
  if (tid == 0) {
    unsigned m = 0;
    unsigned o1 = __hip_atomic_fetch_add(c5A + (wg & 7) * LSTR, 1u,
                                         __ATOMIC_RELAXED, __HIP_MEMORY_SCOPE_AGENT);
    if (o1 == (unsigned)(32 * (t + 1) - 1)) {
      unsigned o2 = __hip_atomic_fetch_add(c5F, 1u,
                                           __ATOMIC_RELAXED, __HIP_MEMORY_SCOPE_AGENT);
      if (o2 == (unsigned)(8 * (t + 1) - 1)) m = 1;
    }
    s_mrg = m;
  }
  __syncthreads();

  // ---- P6 merge (single last-arriving WG; r10-validated algorithm) ----
  if (s_mrg) {
    float* sls = sm;               // [5]
    float* smv = sm + 8;           // [5][5]
    int* smi = (int*)(sm + 40);    // [5][5]
    for (int b = wv; b < NB; b += 4) {
      float q0 = cldf(&p.psum[(lane + 0) * NB + b]);
      float q1 = cldf(&p.psum[(lane + 64) * NB + b]);
      float q2 = cldf(&p.psum[(lane + 128) * NB + b]);
      float q3 = cldf(&p.psum[(lane + 192) * NB + b]);
      float ssum = wredf((q0 + q1) + (q2 + q3));
      float bv[5]; int bix[5];
#pragma unroll
      for (int k = 0; k < 5; k++) { bv[k] = -INFINITY; bix[k] = 0x7fffffff; }
      for (int g = 0; g < 4; g++) {
        int w = lane + g * 64;
#pragma unroll
        for (int k = 0; k < 5; k++) {
          float v = cldf(&p.ptop_v[((size_t)w * NB + b) * 5 + k]);
          int id = cldi(&p.ptop_i[((size_t)w * NB + b) * 5 + k]);
          if (v > bv[4] || (v == bv[4] && id < bix[4])) {
            int kk = 4;
            while (kk > 0 && (v > bv[kk - 1] || (v == bv[kk - 1] && id < bix[kk - 1]))) {
              bv[kk] = bv[kk - 1]; bix[kk] = bix[kk - 1]; kk--;
            }
            bv[kk] = v; bix[kk] = id;
          }
        }
      }
#pragma unroll
      for (int off = 1; off < 64; off <<= 1) {
        float ov[5]; int oi[5];
#pragma unroll
        for (int k = 0; k < 5; k++) { ov[k] = __shfl_xor(bv[k], off, 64); oi[k] = __shfl_xor(bix[k], off, 64); }
        float nv[5]; int ni[5];
        int i2 = 0, j2 = 0;
#pragma unroll
        for (int k = 0; k < 5; k++) {
          bool ta = (bv[i2] > ov[j2]) || (bv[i2] == ov[j2] && bix[i2] < oi[j2]);
          if (ta) { nv[k] = bv[i2]; ni[k] = bix[i2]; i2++; }
          else { nv[k] = ov[j2]; ni[k] = oi[j2]; j2++; }
        }
#pragma unroll
        for (int k = 0; k < 5; k++) { bv[k] = nv[k]; bix[k] = ni[k]; }
      }
      if (lane == 0) {
        sls[b] = logf(ssum);
#pragma unroll
        for (int k = 0; k < 5; k++) { smv[b * 5 + k] = bv[k]; smi[b * 5 + k] = bix[k]; }
      }
    }
    __syncthreads();
    if (tid == 0) {
      float cand[25]; int ctok[25];
      for (int b = 0; b < NB; b++) {
        float sb = cldf(&p.scores[b]), lb = sls[b];
#pragma unroll
        for (int k = 0; k < 5; k++) {
          cand[b * 5 + k] = sb + (smv[b * 5 + k] - lb);
          ctok[b * 5 + k] = smi[b * 5 + k];
        }
      }
      float s5[5]; int f5[5];
#pragma unroll
      for (int k = 0; k < 5; k++) { s5[k] = -INFINITY; f5[k] = 0x7fffffff; }
      for (int f = 0; f < 25; f++) {
        float v = cand[f];
        if (v > s5[4]) {
          int k = 4;
          while (k > 0 && v > s5[k - 1]) { s5[k] = s5[k - 1]; f5[k] = f5[k - 1]; k--; }
          s5[k] = v; f5[k] = f;
        }
      }
      for (int j2 = 0; j2 < 5; j2++) {
        int fl = f5[j2];
        csti(&p.pars[t * NB + j2], fl / 5);
        csti(&p.toks[t * NB + j2], ctok[fl]);
        csti(&p.cur_tok[j2], ctok[fl]);
      }
      for (int j2 = 0; j2 < 5; j2++) cstf(&p.scores[j2], s5[j2]);
      if (t == TO - 1) {  // final backtrack fused here
        int best = 0;
        float bvv = s5[0];
        for (int j = 1; j < NB; j++)
          if (s5[j] > bvv) { bvv = s5[j]; best = j; }
        int beam = best;
        for (int tt = TO - 1; tt >= 0; tt--) {
          p.out[tt] = (float)cldi(&p.toks[tt * NB + beam]);
          beam = cldi(&p.pars[tt * NB + beam]);
        }
        p.out[TO] = bvv;
      }
    }
  }
}

extern "C" void kernel_launch(void* const* d_in, const int* in_sizes, int n_in,
                              void* d_out, int out_size, void* d_ws, size_t ws_size,
                              hipStream_t stream) {
  (void)in_sizes; (void)n_in; (void)out_size; (void)ws_size;
  Params p;
  p.seq  = (const int*)d_in[0];
  p.sosp = (const int*)d_in[3];
  p.emb  = (const float*)d_in[4];
  p.eWi  = (const float*)d_in[5];
  p.eWh  = (const float*)d_in[6];
  p.ebi  = (const float*)d_in[7];
  p.ebh  = (const float*)d_in[8];
  p.dWi  = (const float*)d_in[9];
  p.dWh  = (const float*)d_in[10];
  p.dbi  = (const float*)d_in[11];
  p.dbh  = (const float*)d_in[12];
  p.Wc   = (const float*)d_in[13];
  p.bc   = (const float*)d_in[14];
  p.Wout = (const float*)d_in[15];
  p.bout = (const float*)d_in[16];

  char* w = (char*)d_ws;
  size_t off = 0;
  auto alloc = [&](size_t words) -> char* {
    char* r = w + off;
    off += words * 4;
    off = (off + 255) & ~(size_t)255;
    return r;
  };
  p.bar     = (unsigned*)alloc(64 * LSTR);    // counter/flag lines (memset below)
  p.cur_tok = (int*)alloc(8);
  p.toks    = (int*)alloc(TO * NB);
  p.pars    = (int*)alloc(TO * NB);
  p.ptop_i  = (int*)alloc(256 * NB * 5);
  p.gi0     = (float*)alloc((size_t)TI * G3);
  p.eout    = (float*)alloc((size_t)TI * HH);
  p.h0b     = (float*)alloc(2 * HH);
  p.h1b     = (float*)alloc(2 * HH);
  p.dch     = (float*)alloc(2 * 2 * NB * HH);
  p.cc      = (float*)alloc(NB * HH);
  p.ptop_v  = (float*)alloc(256 * NB * 5);
  p.psum    = (float*)alloc(256 * NB);
  p.scores  = (float*)alloc(8);
  p.out     = (float*)d_out;

  (void)hipMemsetAsync(d_ws, 0, 64 * LSTR * 4, stream);  // zero all lines

  // 195 nodes: 1 + 65 + 1 + 64*2. Internal legs via r8-proven relaxed sync.
  k_e0<<<dim3(256), dim3(NTHR), 0, stream>>>(p);
  for (int k = 0; k <= TI / 2; k++)
    k_e1x2<<<dim3(64), dim3(NTHR), 0, stream>>>(p, k);
  k_d0<<<dim3(64), dim3(NTHR), 0, stream>>>(p);
  for (int t = 0; t < TO; t++) {
    k_gru2<<<dim3(64), dim3(NTHR), 0, stream>>>(p, t);
    k_pa56<<<dim3(256), dim3(NTHR), 0, stream>>>(p, t);
  }
}